// Round 1
// baseline (272.949 us; speedup 1.0000x reference)
//
#include <hip/hip_runtime.h>
#include <hip/hip_bf16.h>

typedef __attribute__((ext_vector_type(4))) float f32x4;
typedef __attribute__((ext_vector_type(8))) short s16x8;

#define D_MODEL 1024
#define D_HEAD  64
#define SEQ_T   4096

__device__ __forceinline__ unsigned short f2bf(float f) {
    unsigned int u = __float_as_uint(f);
    u += 0x7fffu + ((u >> 16) & 1u);
    return (unsigned short)(u >> 16);
}

__device__ __forceinline__ f32x4 mfma_bf16(s16x8 a, s16x8 b, f32x4 c) {
    return __builtin_amdgcn_mfma_f32_16x16x32_bf16(a, b, c, 0, 0, 0);
}

// ---------------------------------------------------------------------------
// Kernel 0: weights [1024][64] f32 (q,k,v) -> wT [192][1024] bf16 (transposed)
// ---------------------------------------------------------------------------
__global__ __launch_bounds__(256) void wconv_kernel(
    const float* __restrict__ wq, const float* __restrict__ wk,
    const float* __restrict__ wv, unsigned short* __restrict__ wT)
{
    int idx = blockIdx.x * 256 + threadIdx.x;        // [0, 3*65536)
    int mat = idx >> 16;
    int rem = idx & 65535;
    int k = rem >> 6, n = rem & 63;
    const float* w = (mat == 0) ? wq : (mat == 1) ? wk : wv;
    wT[(size_t)(mat * 64 + n) * D_MODEL + k] = f2bf(w[rem]);
}

// ---------------------------------------------------------------------------
// Kernel 1: fused QKV projection.  M=16384 rows, K=1024, N=192 (q|k|v).
// 4 waves/block, each wave: 16 rows x 192 cols via 12 MFMA col-tiles.
// q written pre-scaled by 1/8 (exact).  v written transposed: vT[b][d][t].
// ---------------------------------------------------------------------------
__global__ __launch_bounds__(256) void qkv_kernel(
    const float* __restrict__ x,
    const float* __restrict__ bq, const float* __restrict__ bk,
    const float* __restrict__ bv,
    const unsigned short* __restrict__ wT,
    unsigned short* __restrict__ q_ws, unsigned short* __restrict__ k_ws,
    unsigned short* __restrict__ vT_ws)
{
    const int wave = threadIdx.x >> 6;
    const int lane = threadIdx.x & 63;
    const int lr = lane & 15, lg = lane >> 4;
    const int row_base = blockIdx.x * 64 + wave * 16;
    const float* xp = x + (size_t)(row_base + lr) * D_MODEL + lg * 8;

    f32x4 acc[12];
#pragma unroll
    for (int t = 0; t < 12; ++t) acc[t] = (f32x4)0.0f;

    for (int k = 0; k < D_MODEL; k += 32) {
        f32x4 a0 = *(const f32x4*)(xp + k);
        f32x4 a1 = *(const f32x4*)(xp + k + 4);
        s16x8 af;
        af[0] = (short)f2bf(a0[0]); af[1] = (short)f2bf(a0[1]);
        af[2] = (short)f2bf(a0[2]); af[3] = (short)f2bf(a0[3]);
        af[4] = (short)f2bf(a1[0]); af[5] = (short)f2bf(a1[1]);
        af[6] = (short)f2bf(a1[2]); af[7] = (short)f2bf(a1[3]);
#pragma unroll
        for (int t = 0; t < 12; ++t) {
            s16x8 bf = *(const s16x8*)(wT + (size_t)(t * 16 + lr) * D_MODEL + k + lg * 8);
            acc[t] = mfma_bf16(af, bf, acc[t]);
        }
    }

#pragma unroll
    for (int t = 0; t < 12; ++t) {
        int col = t * 16 + lr;
        float bias = (col < 64) ? bq[col] : (col < 128) ? bk[col - 64] : bv[col - 128];
#pragma unroll
        for (int r = 0; r < 4; ++r) {
            int row = row_base + lg * 4 + r;          // = b*4096 + t
            float v = acc[t][r] + bias;
            if (col < 64) {
                q_ws[(size_t)row * 64 + col] = f2bf(v * 0.125f);   // fold softmax scale (exact)
            } else if (col < 128) {
                k_ws[(size_t)row * 64 + (col - 64)] = f2bf(v);
            } else {
                int b = row >> 12, tt = row & 4095;
                vT_ws[(size_t)(b * 64 + (col - 128)) * SEQ_T + tt] = f2bf(v);
            }
        }
    }
}

// ---------------------------------------------------------------------------
// Kernel 2: causal flash attention.  1 wave per block, 16 q-rows per wave,
// KVBLK=64.  P staged through XOR-swizzled LDS (kills D=64 bank conflict).
// ---------------------------------------------------------------------------
__global__ __launch_bounds__(64) void attn_kernel(
    const unsigned short* __restrict__ q_ws, const unsigned short* __restrict__ k_ws,
    const unsigned short* __restrict__ vT_ws, float* __restrict__ out)
{
    __shared__ unsigned short plds[16 * 64];          // 2 KiB, swizzled
    const int lane = threadIdx.x;
    const int lr = lane & 15, lg = lane >> 4;
    const int b  = blockIdx.x >> 8;                   // 256 q-blocks per batch
    const int q0 = (blockIdx.x & 255) * 16;

    const size_t qoff = ((size_t)(b * SEQ_T + q0 + lr)) * 64 + lg * 8;
    s16x8 qf0 = *(const s16x8*)(q_ws + qoff);
    s16x8 qf1 = *(const s16x8*)(q_ws + qoff + 32);

    f32x4 acc[4];
#pragma unroll
    for (int t = 0; t < 4; ++t) acc[t] = (f32x4)0.0f;
    float m[4], lsum[4];
#pragma unroll
    for (int r = 0; r < 4; ++r) { m[r] = -1e30f; lsum[r] = 0.0f; }

    const int kv_end = q0 + 16;
    for (int kv = 0; kv < kv_end; kv += 64) {
        // ---- S = (q*scale) K^T, 16x64 per wave ----
        f32x4 st[4];
#pragma unroll
        for (int t = 0; t < 4; ++t) {
            st[t] = (f32x4)0.0f;
            const unsigned short* kp =
                k_ws + ((size_t)(b * SEQ_T + kv + t * 16 + lr)) * 64 + lg * 8;
            s16x8 k0 = *(const s16x8*)(kp);
            s16x8 k1 = *(const s16x8*)(kp + 32);
            st[t] = mfma_bf16(qf0, k0, st[t]);
            st[t] = mfma_bf16(qf1, k1, st[t]);
        }
        // ---- causal mask + row max ----
        float mx[4] = {-1e30f, -1e30f, -1e30f, -1e30f};
#pragma unroll
        for (int t = 0; t < 4; ++t) {
            int ki = kv + t * 16 + lr;
#pragma unroll
            for (int r = 0; r < 4; ++r) {
                int qi = q0 + lg * 4 + r;
                float s = st[t][r];
                s = (ki > qi) ? -1e30f : s;
                st[t][r] = s;
                mx[r] = fmaxf(mx[r], s);
            }
        }
#pragma unroll
        for (int d = 1; d < 16; d <<= 1)
#pragma unroll
            for (int r = 0; r < 4; ++r) mx[r] = fmaxf(mx[r], __shfl_xor(mx[r], d));

        float corr[4], rs[4];
#pragma unroll
        for (int r = 0; r < 4; ++r) {
            float mn = fmaxf(m[r], mx[r]);
            corr[r] = __expf(m[r] - mn);
            m[r] = mn;
            rs[r] = 0.0f;
        }
        // ---- P = exp(S-m), row sums, stage P (bf16) to swizzled LDS ----
#pragma unroll
        for (int t = 0; t < 4; ++t) {
#pragma unroll
            for (int r = 0; r < 4; ++r) {
                float p = __expf(st[t][r] - m[r]);
                rs[r] += p;
                int row = lg * 4 + r;
                int byte = row * 128 + (t * 16 + lr) * 2;
                byte ^= ((row & 7) << 4);
                *(unsigned short*)((char*)plds + byte) = f2bf(p);
            }
        }
#pragma unroll
        for (int d = 1; d < 16; d <<= 1)
#pragma unroll
            for (int r = 0; r < 4; ++r) rs[r] += __shfl_xor(rs[r], d);
#pragma unroll
        for (int r = 0; r < 4; ++r) lsum[r] = lsum[r] * corr[r] + rs[r];
#pragma unroll
        for (int t = 0; t < 4; ++t)
#pragma unroll
            for (int r = 0; r < 4; ++r) acc[t][r] *= corr[r];
        __syncthreads();
        // ---- O += P V ----
#pragma unroll
        for (int ks = 0; ks < 2; ++ks) {
            int byte = lr * 128 + ks * 64 + lg * 16;
            byte ^= ((lr & 7) << 4);
            s16x8 pf = *(const s16x8*)((const char*)plds + byte);
#pragma unroll
            for (int t = 0; t < 4; ++t) {
                const unsigned short* vp =
                    vT_ws + ((size_t)(b * 64 + t * 16 + lr)) * SEQ_T + kv + ks * 32 + lg * 8;
                s16x8 vf = *(const s16x8*)(vp);
                acc[t] = mfma_bf16(pf, vf, acc[t]);
            }
        }
        __syncthreads();
    }
    // ---- O / l -> out (fp32) ----
#pragma unroll
    for (int t = 0; t < 4; ++t)
#pragma unroll
        for (int r = 0; r < 4; ++r)
            out[((size_t)(b * SEQ_T + q0 + lg * 4 + r)) * 64 + t * 16 + lr] =
                acc[t][r] / lsum[r];
}

// ---------------------------------------------------------------------------
extern "C" void kernel_launch(void* const* d_in, const int* in_sizes, int n_in,
                              void* d_out, int out_size, void* d_ws, size_t ws_size,
                              hipStream_t stream) {
    const float* x  = (const float*)d_in[0];
    const float* wq = (const float*)d_in[1];
    const float* bq = (const float*)d_in[2];
    const float* wk = (const float*)d_in[3];
    const float* bk = (const float*)d_in[4];
    const float* wv = (const float*)d_in[5];
    const float* bv = (const float*)d_in[6];
    float* out = (float*)d_out;

    char* ws = (char*)d_ws;
    unsigned short* wT    = (unsigned short*)(ws);                       // 384 KiB
    unsigned short* q_ws  = (unsigned short*)(ws + 393216);              // 2 MiB
    unsigned short* k_ws  = (unsigned short*)(ws + 393216 + 2097152);    // 2 MiB
    unsigned short* vT_ws = (unsigned short*)(ws + 393216 + 2 * 2097152);// 2 MiB

    wconv_kernel<<<dim3(768), dim3(256), 0, stream>>>(wq, wk, wv, wT);
    qkv_kernel<<<dim3(256), dim3(256), 0, stream>>>(x, bq, bk, bv, wT, q_ws, k_ws, vT_ws);
    attn_kernel<<<dim3(1024), dim3(64), 0, stream>>>(q_ws, k_ws, vT_ws, out);
}

// Round 2
// 153.642 us; speedup vs baseline: 1.7765x; 1.7765x over previous
//
#include <hip/hip_runtime.h>
#include <hip/hip_bf16.h>

typedef __attribute__((ext_vector_type(4))) float f32x4;
typedef __attribute__((ext_vector_type(8))) short s16x8;

#define D_MODEL 1024
#define D_HEAD  64
#define SEQ_T   4096

__device__ __forceinline__ unsigned short f2bf(float f) {
    unsigned int u = __float_as_uint(f);
    u += 0x7fffu + ((u >> 16) & 1u);
    return (unsigned short)(u >> 16);
}

__device__ __forceinline__ f32x4 mfma_bf16(s16x8 a, s16x8 b, f32x4 c) {
    return __builtin_amdgcn_mfma_f32_16x16x32_bf16(a, b, c, 0, 0, 0);
}

// ---------------------------------------------------------------------------
// Kernel 0: weights [1024][64] f32 (q,k,v) -> wT [192][1024] bf16 (transposed)
// ---------------------------------------------------------------------------
__global__ __launch_bounds__(256) void wconv_kernel(
    const float* __restrict__ wq, const float* __restrict__ wk,
    const float* __restrict__ wv, unsigned short* __restrict__ wT)
{
    int idx = blockIdx.x * 256 + threadIdx.x;        // [0, 3*65536)
    int mat = idx >> 16;
    int rem = idx & 65535;
    int k = rem >> 6, n = rem & 63;
    const float* w = (mat == 0) ? wq : (mat == 1) ? wk : wv;
    wT[(size_t)(mat * 64 + n) * D_MODEL + k] = f2bf(w[rem]);
}

// ---------------------------------------------------------------------------
// Kernel 1: fused QKV projection with 2-way K-split.
// Block: 256 threads = 4 waves = 2 row-groups (16 rows) x 2 K-halves.
// Grid: 512 blocks (32 rows each).  kh=1 partials combined via LDS.
// q written pre-scaled by 1/8 (exact).  v written transposed: vT[b][d][t].
// ---------------------------------------------------------------------------
__global__ __launch_bounds__(256) void qkv_kernel(
    const float* __restrict__ x,
    const float* __restrict__ bq, const float* __restrict__ bk,
    const float* __restrict__ bv,
    const unsigned short* __restrict__ wT,
    unsigned short* __restrict__ q_ws, unsigned short* __restrict__ k_ws,
    unsigned short* __restrict__ vT_ws)
{
    __shared__ float sacc[2][16][193];               // pad 193: no bank alias
    const int wave = threadIdx.x >> 6;
    const int lane = threadIdx.x & 63;
    const int rg = wave & 1, kh = wave >> 1;
    const int lr = lane & 15, lg = lane >> 4;
    const int row_base = blockIdx.x * 32 + rg * 16;
    const float* xp = x + (size_t)(row_base + lr) * D_MODEL + kh * 512 + lg * 8;
    const unsigned short* wp = wT + (size_t)(kh * 512) + lg * 8;

    f32x4 acc[12];
#pragma unroll
    for (int t = 0; t < 12; ++t) acc[t] = (f32x4)0.0f;

    f32x4 a0 = *(const f32x4*)(xp);
    f32x4 a1 = *(const f32x4*)(xp + 4);
    for (int k = 0; k < 512; k += 32) {
        f32x4 n0, n1;
        if (k + 32 < 512) {
            n0 = *(const f32x4*)(xp + k + 32);
            n1 = *(const f32x4*)(xp + k + 36);
        }
        s16x8 af;
        af[0] = (short)f2bf(a0[0]); af[1] = (short)f2bf(a0[1]);
        af[2] = (short)f2bf(a0[2]); af[3] = (short)f2bf(a0[3]);
        af[4] = (short)f2bf(a1[0]); af[5] = (short)f2bf(a1[1]);
        af[6] = (short)f2bf(a1[2]); af[7] = (short)f2bf(a1[3]);
#pragma unroll
        for (int t = 0; t < 12; ++t) {
            s16x8 bf = *(const s16x8*)(wp + (size_t)(t * 16 + lr) * D_MODEL + k);
            acc[t] = mfma_bf16(af, bf, acc[t]);
        }
        a0 = n0; a1 = n1;
    }

    if (kh == 1) {
#pragma unroll
        for (int t = 0; t < 12; ++t)
#pragma unroll
            for (int r = 0; r < 4; ++r)
                sacc[rg][lg * 4 + r][t * 16 + lr] = acc[t][r];
    }
    __syncthreads();
    if (kh == 0) {
#pragma unroll
        for (int t = 0; t < 12; ++t) {
            int col = t * 16 + lr;
            float bias = (col < 64) ? bq[col] : (col < 128) ? bk[col - 64] : bv[col - 128];
#pragma unroll
            for (int r = 0; r < 4; ++r) {
                int row = row_base + lg * 4 + r;      // = b*4096 + t
                float v = acc[t][r] + sacc[rg][lg * 4 + r][t * 16 + lr] + bias;
                if (col < 64) {
                    q_ws[(size_t)row * 64 + col] = f2bf(v * 0.125f);  // fold softmax scale
                } else if (col < 128) {
                    k_ws[(size_t)row * 64 + (col - 64)] = f2bf(v);
                } else {
                    int b = row >> 12, tt = row & 4095;
                    vT_ws[(size_t)(b * 64 + (col - 128)) * SEQ_T + tt] = f2bf(v);
                }
            }
        }
    }
}

// ---------------------------------------------------------------------------
// Kernel 2: causal flash attention with 4-way KV-split per block.
// Block: 256 threads = 4 waves; wave w handles kv-tiles c = w, w+4, ...
// Each wave: private online softmax + private double-buffered P LDS
// (wave-local lgkmcnt sync, no block barrier in loop).  Block-wide combine
// of (m, l, acc) at the end.
// ---------------------------------------------------------------------------
__global__ __launch_bounds__(256) void attn_kernel(
    const unsigned short* __restrict__ q_ws, const unsigned short* __restrict__ k_ws,
    const unsigned short* __restrict__ vT_ws, float* __restrict__ out)
{
    __shared__ unsigned short plds[4][2][16 * 64];   // 16 KiB, per-wave dbuf, swizzled
    __shared__ float macc[4][16][65];                // 16.6 KiB, pad 65
    __shared__ float sml[4][2][16];                  // m, l per wave per row
    const int lane = threadIdx.x & 63;
    const int w = threadIdx.x >> 6;
    const int lr = lane & 15, lg = lane >> 4;
    const int b  = blockIdx.x >> 8;                  // 256 q-blocks per batch
    const int q0 = (blockIdx.x & 255) * 16;

    const size_t qoff = ((size_t)(b * SEQ_T + q0 + lr)) * 64 + lg * 8;
    s16x8 qf0 = *(const s16x8*)(q_ws + qoff);
    s16x8 qf1 = *(const s16x8*)(q_ws + qoff + 32);

    f32x4 acc[4];
#pragma unroll
    for (int t = 0; t < 4; ++t) acc[t] = (f32x4)0.0f;
    float m[4], lsum[4];
#pragma unroll
    for (int r = 0; r < 4; ++r) { m[r] = -1e30f; lsum[r] = 0.0f; }

    const int ntiles = (q0 + 16 + 63) >> 6;
    int it = 0;
    for (int c = w; c < ntiles; c += 4, ++it) {
        const int kv = c * 64;
        // ---- S = (q*scale) K^T, 16x64 per wave ----
        f32x4 st[4];
#pragma unroll
        for (int t = 0; t < 4; ++t) {
            st[t] = (f32x4)0.0f;
            const unsigned short* kp =
                k_ws + ((size_t)(b * SEQ_T + kv + t * 16 + lr)) * 64 + lg * 8;
            s16x8 k0 = *(const s16x8*)(kp);
            s16x8 k1 = *(const s16x8*)(kp + 32);
            st[t] = mfma_bf16(qf0, k0, st[t]);
            st[t] = mfma_bf16(qf1, k1, st[t]);
        }
        // ---- causal mask + row max ----
        float mx[4] = {-1e30f, -1e30f, -1e30f, -1e30f};
#pragma unroll
        for (int t = 0; t < 4; ++t) {
            int ki = kv + t * 16 + lr;
#pragma unroll
            for (int r = 0; r < 4; ++r) {
                int qi = q0 + lg * 4 + r;
                float s = st[t][r];
                s = (ki > qi) ? -1e30f : s;
                st[t][r] = s;
                mx[r] = fmaxf(mx[r], s);
            }
        }
#pragma unroll
        for (int d = 1; d < 16; d <<= 1)
#pragma unroll
            for (int r = 0; r < 4; ++r) mx[r] = fmaxf(mx[r], __shfl_xor(mx[r], d));

        float corr[4], rs[4];
#pragma unroll
        for (int r = 0; r < 4; ++r) {
            float mn = fmaxf(m[r], mx[r]);
            corr[r] = __expf(m[r] - mn);
            m[r] = mn;
            rs[r] = 0.0f;
        }
        // ---- P = exp(S-m) (guarded: fully-masked rows must give p=0),
        //      row sums, stage P (bf16) to this wave's swizzled LDS buffer ----
        unsigned short* pb = &plds[w][it & 1][0];
#pragma unroll
        for (int t = 0; t < 4; ++t) {
#pragma unroll
            for (int r = 0; r < 4; ++r) {
                float s = st[t][r];
                float p = (s > -1e29f) ? __expf(s - m[r]) : 0.0f;
                rs[r] += p;
                int row = lg * 4 + r;
                int byte = row * 128 + (t * 16 + lr) * 2;
                byte ^= ((row & 7) << 4);
                *(unsigned short*)((char*)pb + byte) = f2bf(p);
            }
        }
#pragma unroll
        for (int d = 1; d < 16; d <<= 1)
#pragma unroll
            for (int r = 0; r < 4; ++r) rs[r] += __shfl_xor(rs[r], d);
#pragma unroll
        for (int r = 0; r < 4; ++r) lsum[r] = lsum[r] * corr[r] + rs[r];
#pragma unroll
        for (int t = 0; t < 4; ++t)
#pragma unroll
            for (int r = 0; r < 4; ++r) acc[t][r] *= corr[r];
        // wave-local write->read ordering (LDS is wave-private; rule #18)
        asm volatile("s_waitcnt lgkmcnt(0)" ::: "memory");
        __builtin_amdgcn_sched_barrier(0);
        // ---- O += P V ----
#pragma unroll
        for (int ks = 0; ks < 2; ++ks) {
            int byte = lr * 128 + ks * 64 + lg * 16;
            byte ^= ((lr & 7) << 4);
            s16x8 pf = *(const s16x8*)((const char*)pb + byte);
#pragma unroll
            for (int t = 0; t < 4; ++t) {
                const unsigned short* vp =
                    vT_ws + ((size_t)(b * 64 + t * 16 + lr)) * SEQ_T + kv + ks * 32 + lg * 8;
                s16x8 vf = *(const s16x8*)(vp);
                acc[t] = mfma_bf16(pf, vf, acc[t]);
            }
        }
        asm volatile("s_waitcnt lgkmcnt(0)" ::: "memory");
        __builtin_amdgcn_sched_barrier(0);
    }

    // ---- publish partials ----
#pragma unroll
    for (int t = 0; t < 4; ++t)
#pragma unroll
        for (int r = 0; r < 4; ++r)
            macc[w][lg * 4 + r][t * 16 + lr] = acc[t][r];
    if (lr == 0) {
#pragma unroll
        for (int r = 0; r < 4; ++r) {
            sml[w][0][lg * 4 + r] = m[r];
            sml[w][1][lg * 4 + r] = lsum[r];
        }
    }
    __syncthreads();

    // ---- block-wide combine: wave w owns col-tile w ----
    const int col = w * 16 + lr;
#pragma unroll
    for (int r = 0; r < 4; ++r) {
        const int row = lg * 4 + r;
        float M = -1e30f;
#pragma unroll
        for (int ww = 0; ww < 4; ++ww) M = fmaxf(M, sml[ww][0][row]);
        float L = 0.0f, O = 0.0f;
#pragma unroll
        for (int ww = 0; ww < 4; ++ww) {
            float e = __expf(sml[ww][0][row] - M);   // underflows to 0 for idle waves
            L += sml[ww][1][row] * e;
            O += macc[ww][row][col] * e;
        }
        out[((size_t)(b * SEQ_T + q0 + row)) * 64 + col] = O / L;
    }
}

// ---------------------------------------------------------------------------
extern "C" void kernel_launch(void* const* d_in, const int* in_sizes, int n_in,
                              void* d_out, int out_size, void* d_ws, size_t ws_size,
                              hipStream_t stream) {
    const float* x  = (const float*)d_in[0];
    const float* wq = (const float*)d_in[1];
    const float* bq = (const float*)d_in[2];
    const float* wk = (const float*)d_in[3];
    const float* bk = (const float*)d_in[4];
    const float* wv = (const float*)d_in[5];
    const float* bv = (const float*)d_in[6];
    float* out = (float*)d_out;

    char* ws = (char*)d_ws;
    unsigned short* wT    = (unsigned short*)(ws);                       // 384 KiB
    unsigned short* q_ws  = (unsigned short*)(ws + 393216);              // 2 MiB
    unsigned short* k_ws  = (unsigned short*)(ws + 393216 + 2097152);    // 2 MiB
    unsigned short* vT_ws = (unsigned short*)(ws + 393216 + 2 * 2097152);// 2 MiB

    wconv_kernel<<<dim3(768), dim3(256), 0, stream>>>(wq, wk, wv, wT);
    qkv_kernel<<<dim3(512), dim3(256), 0, stream>>>(x, bq, bk, bv, wT, q_ws, k_ws, vT_ws);
    attn_kernel<<<dim3(1024), dim3(256), 0, stream>>>(q_ws, k_ws, vT_ws, out);
}

// Round 3
// 120.835 us; speedup vs baseline: 2.2589x; 1.2715x over previous
//
#include <hip/hip_runtime.h>
#include <hip/hip_bf16.h>

typedef __attribute__((ext_vector_type(4)))  float f32x4;
typedef __attribute__((ext_vector_type(16))) float f32x16;
typedef __attribute__((ext_vector_type(8)))  short s16x8;
typedef __attribute__((ext_vector_type(4)))  unsigned int u32x4;

#define D_MODEL 1024
#define D_HEAD  64
#define SEQ_T   4096

__device__ __forceinline__ unsigned short f2bf(float f) {
    unsigned int u = __float_as_uint(f);
    u += 0x7fffu + ((u >> 16) & 1u);
    return (unsigned short)(u >> 16);
}

__device__ __forceinline__ unsigned int cvtpk_bf16(float lo, float hi) {
    unsigned int r;
    asm("v_cvt_pk_bf16_f32 %0, %1, %2" : "=v"(r) : "v"(lo), "v"(hi));
    return r;
}

__device__ __forceinline__ f32x4 mfma16(s16x8 a, s16x8 b, f32x4 c) {
    return __builtin_amdgcn_mfma_f32_16x16x32_bf16(a, b, c, 0, 0, 0);
}
__device__ __forceinline__ f32x16 mfma32(s16x8 a, s16x8 b, f32x16 c) {
    return __builtin_amdgcn_mfma_f32_32x32x16_bf16(a, b, c, 0, 0, 0);
}

// ---------------------------------------------------------------------------
// Kernel 0: weights [1024][64] f32 (q,k,v) -> wT [192][1024] bf16 (transposed)
// ---------------------------------------------------------------------------
__global__ __launch_bounds__(256) void wconv_kernel(
    const float* __restrict__ wq, const float* __restrict__ wk,
    const float* __restrict__ wv, unsigned short* __restrict__ wT)
{
    int idx = blockIdx.x * 256 + threadIdx.x;        // [0, 3*65536)
    int mat = idx >> 16;
    int rem = idx & 65535;
    int k = rem >> 6, n = rem & 63;
    const float* w = (mat == 0) ? wq : (mat == 1) ? wk : wv;
    wT[(size_t)(mat * 64 + n) * D_MODEL + k] = f2bf(w[rem]);
}

// ---------------------------------------------------------------------------
// Kernel 1: fused QKV projection, 4-way K-split.
// Block: 256 thr = 4 waves, all on the same 16 rows; wave w covers K-range
// [256w, 256w+256).  Grid 1024 (16 rows each) -> 4 blocks/CU, 4 waves/SIMD.
// Waves 1-3 publish partials to LDS; wave 0 combines + bias + writes.
// q pre-scaled by 1/8 (exact).  v written transposed: vT[b][d][t].
// ---------------------------------------------------------------------------
__global__ __launch_bounds__(256) void qkv_kernel(
    const float* __restrict__ x,
    const float* __restrict__ bq, const float* __restrict__ bk,
    const float* __restrict__ bv,
    const unsigned short* __restrict__ wT,
    unsigned short* __restrict__ q_ws, unsigned short* __restrict__ k_ws,
    unsigned short* __restrict__ vT_ws)
{
    __shared__ float sacc[3][16][193];               // 37 KiB, stride 193 (odd)
    const int wave = threadIdx.x >> 6;               // K-split index
    const int lane = threadIdx.x & 63;
    const int lr = lane & 15, lg = lane >> 4;
    const int row_base = blockIdx.x * 16;
    const float* xp = x + (size_t)(row_base + lr) * D_MODEL + wave * 256 + lg * 8;
    const unsigned short* wp = wT + wave * 256 + lg * 8;

    f32x4 acc[12];
#pragma unroll
    for (int t = 0; t < 12; ++t) acc[t] = (f32x4)0.0f;

    f32x4 a0 = *(const f32x4*)(xp);
    f32x4 a1 = *(const f32x4*)(xp + 4);
    for (int k = 0; k < 256; k += 32) {
        f32x4 n0, n1;
        if (k + 32 < 256) {
            n0 = *(const f32x4*)(xp + k + 32);
            n1 = *(const f32x4*)(xp + k + 36);
        }
        u32x4 pk;
        pk[0] = cvtpk_bf16(a0[0], a0[1]);
        pk[1] = cvtpk_bf16(a0[2], a0[3]);
        pk[2] = cvtpk_bf16(a1[0], a1[1]);
        pk[3] = cvtpk_bf16(a1[2], a1[3]);
        s16x8 af = __builtin_bit_cast(s16x8, pk);
#pragma unroll
        for (int t = 0; t < 12; ++t) {
            s16x8 bf = *(const s16x8*)(wp + (size_t)(t * 16 + lr) * D_MODEL + k);
            acc[t] = mfma16(af, bf, acc[t]);
        }
        a0 = n0; a1 = n1;
    }

    if (wave != 0) {
#pragma unroll
        for (int t = 0; t < 12; ++t)
#pragma unroll
            for (int r = 0; r < 4; ++r)
                sacc[wave - 1][lg * 4 + r][t * 16 + lr] = acc[t][r];
    }
    __syncthreads();
    if (wave == 0) {
#pragma unroll
        for (int t = 0; t < 12; ++t) {
            int col = t * 16 + lr;
            float bias = (col < 64) ? bq[col] : (col < 128) ? bk[col - 64] : bv[col - 128];
#pragma unroll
            for (int r = 0; r < 4; ++r) {
                int row = row_base + lg * 4 + r;      // = b*4096 + t
                float v = acc[t][r] + bias;
#pragma unroll
                for (int ww = 0; ww < 3; ++ww) v += sacc[ww][lg * 4 + r][t * 16 + lr];
                if (col < 64) {
                    q_ws[(size_t)row * 64 + col] = f2bf(v * 0.125f);  // fold softmax scale
                } else if (col < 128) {
                    k_ws[(size_t)row * 64 + (col - 64)] = f2bf(v);
                } else {
                    int b = row >> 12, tt = row & 4095;
                    vT_ws[(size_t)(b * 64 + (col - 128)) * SEQ_T + tt] = f2bf(v);
                }
            }
        }
    }
}

// ---------------------------------------------------------------------------
// Kernel 2: causal flash attention, swapped-QK in-register softmax (32x32).
// Block: 512 thr = 8 waves, all on the same 32 q-rows; wave w handles kv
// tiles c = w, w+8, ... (KVBLK=32).  No LDS / barriers in main loop:
//   S^T = mfma32(A=K, B=Q^T)  -> lane holds 16 P-values of q-row (lane&31)
//   softmax in-register (15 ops + 1 shfl_xor(32))
//   P -> bf16 B-frags via v_cvt_pk_bf16_f32 + 8 half-swaps (T12)
//   O^T += mfma32(A=V^T, B=P^T) -> O cols lane-local q, rescale lane-local
// Two-stage (8->4->1) combine via LDS at the end.
// Blocks ordered longest-q0-first for tail packing.
// ---------------------------------------------------------------------------
__global__ __launch_bounds__(512) void attn_kernel(
    const unsigned short* __restrict__ q_ws, const unsigned short* __restrict__ k_ws,
    const unsigned short* __restrict__ vT_ws, float* __restrict__ out)
{
    __shared__ float solds[4][32][66];               // 33 KiB
    __shared__ float sml[4][2][32];                  // 1 KiB
    const int lane = threadIdx.x & 63;
    const int w = threadIdx.x >> 6;                  // 0..7
    const int q = lane & 31;
    const int hi = lane >> 5;
    const int khalf = 4 * hi;
    const int b = blockIdx.x & 3;
    const int qb = blockIdx.x >> 2;                  // 0..127
    const int q0 = SEQ_T - 32 * (qb + 1);            // longest first
    const int ntiles = (q0 >> 5) + 1;

    // Q B-fragments (col = q = lane&31, k-dim d = hi*8 + j + 16*dstep)
    const unsigned short* qrow = q_ws + ((size_t)(b * SEQ_T + q0 + q)) * 64 + hi * 8;
    s16x8 qf[4];
#pragma unroll
    for (int d = 0; d < 4; ++d) qf[d] = *(const s16x8*)(qrow + d * 16);

    f32x16 o0 = (f32x16)0.0f, o1 = (f32x16)0.0f;
    float m = -1e30f, lsum = 0.0f;

    const unsigned short* kbase = k_ws + ((size_t)(b * SEQ_T + q)) * 64 + hi * 8;
    const unsigned short* vb0 = vT_ws + ((size_t)(b * 64 + q)) * SEQ_T + hi * 8;
    const unsigned short* vb1 = vT_ws + ((size_t)(b * 64 + 32 + q)) * SEQ_T + hi * 8;

    int c = w;
    if (c < ntiles) {
        s16x8 kf[4];
        {
            const unsigned short* kp = kbase + (size_t)(c << 5) * 64;
#pragma unroll
            for (int d = 0; d < 4; ++d) kf[d] = *(const s16x8*)(kp + d * 16);
        }
        for (; c < ntiles; c += 8) {
            const int kv = c << 5;
            // ---- S^T = K Q^T ----
            f32x16 s = (f32x16)0.0f;
#pragma unroll
            for (int d = 0; d < 4; ++d) s = mfma32(kf[d], qf[d], s);
            // ---- prefetch next K tile ----
            {
                const int cn = (c + 8 < ntiles) ? c + 8 : 0;
                const unsigned short* kp = kbase + (size_t)(cn << 5) * 64;
#pragma unroll
                for (int d = 0; d < 4; ++d) kf[d] = *(const s16x8*)(kp + d * 16);
            }
            // ---- V^T A-fragments for this tile ----
            s16x8 vf00 = *(const s16x8*)(vb0 + kv);
            s16x8 vf01 = *(const s16x8*)(vb0 + kv + 16);
            s16x8 vf10 = *(const s16x8*)(vb1 + kv);
            s16x8 vf11 = *(const s16x8*)(vb1 + kv + 16);
            // ---- causal mask (diagonal tile only) ----
            if (kv + 32 > q0) {
                const int qg = q0 + q;
#pragma unroll
                for (int i = 0; i < 16; ++i) {
                    int kk = kv + (i & 3) + 8 * (i >> 2) + khalf;
                    if (kk > qg) s[i] = -1e30f;
                }
            }
            // ---- row max (in-register + one half-swap) ----
            float mx = s[0];
#pragma unroll
            for (int i = 1; i < 16; ++i) mx = fmaxf(mx, s[i]);
            mx = fmaxf(mx, __shfl_xor(mx, 32));
            const float mnew = fmaxf(m, mx);
            const float corr = __expf(m - mnew);
            m = mnew;
            // ---- P = exp(S - m), row sum ----
            float rs = 0.0f;
#pragma unroll
            for (int i = 0; i < 16; ++i) {
                float p = __expf(s[i] - mnew);
                s[i] = p;
                rs += p;
            }
            rs += __shfl_xor(rs, 32);
            lsum = lsum * corr + rs;
#pragma unroll
            for (int i = 0; i < 16; ++i) { o0[i] *= corr; o1[i] *= corr; }
            // ---- pack P -> B-fragments (cvt_pk + half swaps) ----
            unsigned int cc[8], pc[8];
#pragma unroll
            for (int i = 0; i < 8; ++i) cc[i] = cvtpk_bf16(s[2 * i], s[2 * i + 1]);
#pragma unroll
            for (int i = 0; i < 8; ++i)
                pc[i] = (unsigned int)__shfl_xor((int)cc[i], 32);
            u32x4 w0, w1;
            w0[0] = hi ? pc[2] : cc[0]; w0[1] = hi ? pc[3] : cc[1];
            w0[2] = hi ? cc[2] : pc[0]; w0[3] = hi ? cc[3] : pc[1];
            w1[0] = hi ? pc[6] : cc[4]; w1[1] = hi ? pc[7] : cc[5];
            w1[2] = hi ? cc[6] : pc[4]; w1[3] = hi ? cc[7] : pc[5];
            s16x8 pb0 = __builtin_bit_cast(s16x8, w0);
            s16x8 pb1 = __builtin_bit_cast(s16x8, w1);
            // ---- O^T += V^T P^T ----
            o0 = mfma32(vf00, pb0, o0);
            o0 = mfma32(vf01, pb1, o0);
            o1 = mfma32(vf10, pb0, o1);
            o1 = mfma32(vf11, pb1, o1);
        }
    }

    // ---- stage A: waves 4..7 publish ----
    if (w >= 4) {
        const int sw = w - 4;
#pragma unroll
        for (int i = 0; i < 16; ++i) {
            int d = (i & 3) + 8 * (i >> 2) + khalf;
            solds[sw][q][d] = o0[i];
            solds[sw][q][d + 32] = o1[i];
        }
        if (!hi) { sml[sw][0][q] = m; sml[sw][1][q] = lsum; }
    }
    __syncthreads();
    // ---- stage B: waves 0..3 merge partner w+4 ----
    if (w < 4) {
        const float mp = sml[w][0][q], lp = sml[w][1][q];
        const float M = fmaxf(m, mp);
        const float e = __expf(m - M), ep = __expf(mp - M);
        m = M;
        lsum = lsum * e + lp * ep;
#pragma unroll
        for (int i = 0; i < 16; ++i) {
            int d = (i & 3) + 8 * (i >> 2) + khalf;
            o0[i] = o0[i] * e + solds[w][q][d] * ep;
            o1[i] = o1[i] * e + solds[w][q][d + 32] * ep;
        }
    }
    __syncthreads();
    if (w < 4) {
#pragma unroll
        for (int i = 0; i < 16; ++i) {
            int d = (i & 3) + 8 * (i >> 2) + khalf;
            solds[w][q][d] = o0[i];
            solds[w][q][d + 32] = o1[i];
        }
        if (!hi) { sml[w][0][q] = m; sml[w][1][q] = lsum; }
    }
    __syncthreads();
    // ---- final: 512 threads, 4 outputs each, coalesced f32x4 stores ----
    {
        const int t = threadIdx.x;
        const int qq = t >> 4, d0 = (t & 15) * 4;
        float M = -1e30f;
#pragma unroll
        for (int ww = 0; ww < 4; ++ww) M = fmaxf(M, sml[ww][0][qq]);
        float L = 0.0f;
        float O[4] = {0.0f, 0.0f, 0.0f, 0.0f};
#pragma unroll
        for (int ww = 0; ww < 4; ++ww) {
            float e = __expf(sml[ww][0][qq] - M);
            L += sml[ww][1][qq] * e;
#pragma unroll
            for (int j = 0; j < 4; ++j) O[j] += solds[ww][qq][d0 + j] * e;
        }
        f32x4 res;
#pragma unroll
        for (int j = 0; j < 4; ++j) res[j] = O[j] / L;
        *(f32x4*)(out + ((size_t)(b * SEQ_T + q0 + qq)) * 64 + d0) = res;
    }
}

// ---------------------------------------------------------------------------
extern "C" void kernel_launch(void* const* d_in, const int* in_sizes, int n_in,
                              void* d_out, int out_size, void* d_ws, size_t ws_size,
                              hipStream_t stream) {
    const float* x  = (const float*)d_in[0];
    const float* wq = (const float*)d_in[1];
    const float* bq = (const float*)d_in[2];
    const float* wk = (const float*)d_in[3];
    const float* bk = (const float*)d_in[4];
    const float* wv = (const float*)d_in[5];
    const float* bv = (const float*)d_in[6];
    float* out = (float*)d_out;

    char* ws = (char*)d_ws;
    unsigned short* wT    = (unsigned short*)(ws);                       // 384 KiB
    unsigned short* q_ws  = (unsigned short*)(ws + 393216);              // 2 MiB
    unsigned short* k_ws  = (unsigned short*)(ws + 393216 + 2097152);    // 2 MiB
    unsigned short* vT_ws = (unsigned short*)(ws + 393216 + 2 * 2097152);// 2 MiB

    wconv_kernel<<<dim3(768), dim3(256), 0, stream>>>(wq, wk, wv, wT);
    qkv_kernel<<<dim3(1024), dim3(256), 0, stream>>>(x, bq, bk, bv, wT, q_ws, k_ws, vT_ws);
    attn_kernel<<<dim3(512), dim3(512), 0, stream>>>(q_ws, k_ws, vT_ws, out);
}

// Round 5
// 112.007 us; speedup vs baseline: 2.4369x; 1.0788x over previous
//
#include <hip/hip_runtime.h>
#include <hip/hip_bf16.h>

typedef __attribute__((ext_vector_type(4)))  float f32x4;
typedef __attribute__((ext_vector_type(16))) float f32x16;
typedef __attribute__((ext_vector_type(8)))  short s16x8;
typedef __attribute__((ext_vector_type(4)))  unsigned int u32x4;

#define D_MODEL 1024
#define D_HEAD  64
#define SEQ_T   4096

__device__ __forceinline__ unsigned short f2bf(float f) {
    unsigned int u = __float_as_uint(f);
    u += 0x7fffu + ((u >> 16) & 1u);
    return (unsigned short)(u >> 16);
}

__device__ __forceinline__ unsigned int cvtpk_bf16(float lo, float hi) {
    unsigned int r;
    asm("v_cvt_pk_bf16_f32 %0, %1, %2" : "=v"(r) : "v"(lo), "v"(hi));
    return r;
}

__device__ __forceinline__ f32x4 mfma16(s16x8 a, s16x8 b, f32x4 c) {
    return __builtin_amdgcn_mfma_f32_16x16x32_bf16(a, b, c, 0, 0, 0);
}
__device__ __forceinline__ f32x16 mfma32(s16x8 a, s16x8 b, f32x16 c) {
    return __builtin_amdgcn_mfma_f32_32x32x16_bf16(a, b, c, 0, 0, 0);
}

// ---------------------------------------------------------------------------
// Kernel 0: weights [1024][64] f32 (q,k,v) -> wT [192][1024] bf16 (transposed)
// ---------------------------------------------------------------------------
__global__ __launch_bounds__(256) void wconv_kernel(
    const float* __restrict__ wq, const float* __restrict__ wk,
    const float* __restrict__ wv, unsigned short* __restrict__ wT)
{
    int idx = blockIdx.x * 256 + threadIdx.x;        // [0, 3*65536)
    int mat = idx >> 16;
    int rem = idx & 65535;
    int k = rem >> 6, n = rem & 63;
    const float* w = (mat == 0) ? wq : (mat == 1) ? wk : wv;
    wT[(size_t)(mat * 64 + n) * D_MODEL + k] = f2bf(w[rem]);
}

// ---------------------------------------------------------------------------
// Kernel 1: fused QKV projection, 2-way K-split, register-double-buffered B.
// Block: 256 thr = 4 waves = 2 row-groups (16 rows) x 2 K-halves.
// Grid 512 (32 rows each) -> 2048 waves = 2 waves/SIMD.
// Inner loop prefetches next iter's 12 weight fragments + next x chunk into
// registers while MFMAing the current ones (hides ~200cy L2 latency).
// kh=1 partials combined via LDS.  q pre-scaled by 1/8 (exact).
// v written transposed: vT[b][d][t].
// ---------------------------------------------------------------------------
__global__ __launch_bounds__(256, 2) void qkv_kernel(
    const float* __restrict__ x,
    const float* __restrict__ bq, const float* __restrict__ bk,
    const float* __restrict__ bv,
    const unsigned short* __restrict__ wT,
    unsigned short* __restrict__ q_ws, unsigned short* __restrict__ k_ws,
    unsigned short* __restrict__ vT_ws)
{
    __shared__ float sacc[2][16][193];               // 24.7 KiB, stride 193 (odd)
    const int wave = threadIdx.x >> 6;
    const int lane = threadIdx.x & 63;
    const int rg = wave & 1, kh = wave >> 1;
    const int lr = lane & 15, lg = lane >> 4;
    const int row_base = blockIdx.x * 32 + rg * 16;
    const float* xp = x + (size_t)(row_base + lr) * D_MODEL + kh * 512 + lg * 8;
    const unsigned short* wp = wT + kh * 512 + lg * 8;

    f32x4 acc[12];
#pragma unroll
    for (int t = 0; t < 12; ++t) acc[t] = (f32x4)0.0f;

    // prime: current B-frags + current x chunk
    s16x8 bcur[12];
#pragma unroll
    for (int t = 0; t < 12; ++t)
        bcur[t] = *(const s16x8*)(wp + (size_t)(t * 16 + lr) * D_MODEL);
    f32x4 a0 = *(const f32x4*)(xp);
    f32x4 a1 = *(const f32x4*)(xp + 4);

#pragma unroll
    for (int k = 0; k < 512; k += 32) {
        s16x8 bnext[12];
        f32x4 n0, n1;
        const bool more = (k + 32 < 512);
        if (more) {
            // issue next-iter loads first: in flight during this iter's MFMAs
            n0 = *(const f32x4*)(xp + k + 32);
            n1 = *(const f32x4*)(xp + k + 36);
#pragma unroll
            for (int t = 0; t < 12; ++t)
                bnext[t] = *(const s16x8*)(wp + (size_t)(t * 16 + lr) * D_MODEL + k + 32);
        }
        u32x4 pk;
        pk[0] = cvtpk_bf16(a0[0], a0[1]);
        pk[1] = cvtpk_bf16(a0[2], a0[3]);
        pk[2] = cvtpk_bf16(a1[0], a1[1]);
        pk[3] = cvtpk_bf16(a1[2], a1[3]);
        s16x8 af = __builtin_bit_cast(s16x8, pk);
#pragma unroll
        for (int t = 0; t < 12; ++t)
            acc[t] = mfma16(af, bcur[t], acc[t]);
        if (more) {
#pragma unroll
            for (int t = 0; t < 12; ++t) bcur[t] = bnext[t];
            a0 = n0; a1 = n1;
        }
    }

    if (kh == 1) {
#pragma unroll
        for (int t = 0; t < 12; ++t)
#pragma unroll
            for (int r = 0; r < 4; ++r)
                sacc[rg][lg * 4 + r][t * 16 + lr] = acc[t][r];
    }
    __syncthreads();
    if (kh == 0) {
#pragma unroll
        for (int t = 0; t < 12; ++t) {
            int col = t * 16 + lr;
            float bias = (col < 64) ? bq[col] : (col < 128) ? bk[col - 64] : bv[col - 128];
#pragma unroll
            for (int r = 0; r < 4; ++r) {
                int row = row_base + lg * 4 + r;      // = b*4096 + t
                float v = acc[t][r] + sacc[rg][lg * 4 + r][t * 16 + lr] + bias;
                if (col < 64) {
                    q_ws[(size_t)row * 64 + col] = f2bf(v * 0.125f);  // fold softmax scale
                } else if (col < 128) {
                    k_ws[(size_t)row * 64 + (col - 64)] = f2bf(v);
                } else {
                    int b = row >> 12, tt = row & 4095;
                    vT_ws[(size_t)(b * 64 + (col - 128)) * SEQ_T + tt] = f2bf(v);
                }
            }
        }
    }
}

// ---------------------------------------------------------------------------
// Kernel 2: causal flash attention, swapped-QK in-register softmax (32x32).
// Block: 512 thr = 8 waves, all on the same 32 q-rows; wave w handles kv
// tiles c = w, w+8, ... (KVBLK=32).  No LDS / barriers in main loop:
//   S^T = mfma32(A=K, B=Q^T)  -> lane holds 16 P-values of q-row (lane&31)
//   softmax in-register (15 ops + 1 shfl_xor(32))
//   P -> bf16 B-frags via v_cvt_pk_bf16_f32 + 8 half-swaps (T12)
//   O^T += mfma32(A=V^T, B=P^T) -> O cols lane-local q, rescale lane-local
// s_setprio(1) around MFMA clusters (T5).  Two-stage (8->4->1) LDS combine.
// Blocks ordered longest-q0-first for tail packing.
// ---------------------------------------------------------------------------
__global__ __launch_bounds__(512) void attn_kernel(
    const unsigned short* __restrict__ q_ws, const unsigned short* __restrict__ k_ws,
    const unsigned short* __restrict__ vT_ws, float* __restrict__ out)
{
    __shared__ float solds[4][32][66];               // 33 KiB
    __shared__ float sml[4][2][32];                  // 1 KiB
    const int lane = threadIdx.x & 63;
    const int w = threadIdx.x >> 6;                  // 0..7
    const int q = lane & 31;
    const int hi = lane >> 5;
    const int khalf = 4 * hi;
    const int b = blockIdx.x & 3;
    const int qb = blockIdx.x >> 2;                  // 0..127
    const int q0 = SEQ_T - 32 * (qb + 1);            // longest first
    const int ntiles = (q0 >> 5) + 1;

    // Q B-fragments (col = q = lane&31, k-dim d = hi*8 + j + 16*dstep)
    const unsigned short* qrow = q_ws + ((size_t)(b * SEQ_T + q0 + q)) * 64 + hi * 8;
    s16x8 qf[4];
#pragma unroll
    for (int d = 0; d < 4; ++d) qf[d] = *(const s16x8*)(qrow + d * 16);

    f32x16 o0 = (f32x16)0.0f, o1 = (f32x16)0.0f;
    float m = -1e30f, lsum = 0.0f;

    const unsigned short* kbase = k_ws + ((size_t)(b * SEQ_T + q)) * 64 + hi * 8;
    const unsigned short* vb0 = vT_ws + ((size_t)(b * 64 + q)) * SEQ_T + hi * 8;
    const unsigned short* vb1 = vT_ws + ((size_t)(b * 64 + 32 + q)) * SEQ_T + hi * 8;

    int c = w;
    if (c < ntiles) {
        s16x8 kf[4];
        {
            const unsigned short* kp = kbase + (size_t)(c << 5) * 64;
#pragma unroll
            for (int d = 0; d < 4; ++d) kf[d] = *(const s16x8*)(kp + d * 16);
        }
        for (; c < ntiles; c += 8) {
            const int kv = c << 5;
            // ---- S^T = K Q^T ----
            f32x16 s = (f32x16)0.0f;
            __builtin_amdgcn_s_setprio(1);
#pragma unroll
            for (int d = 0; d < 4; ++d) s = mfma32(kf[d], qf[d], s);
            __builtin_amdgcn_s_setprio(0);
            // ---- prefetch next K tile ----
            {
                const int cn = (c + 8 < ntiles) ? c + 8 : 0;
                const unsigned short* kp = kbase + (size_t)(cn << 5) * 64;
#pragma unroll
                for (int d = 0; d < 4; ++d) kf[d] = *(const s16x8*)(kp + d * 16);
            }
            // ---- V^T A-fragments for this tile ----
            s16x8 vf00 = *(const s16x8*)(vb0 + kv);
            s16x8 vf01 = *(const s16x8*)(vb0 + kv + 16);
            s16x8 vf10 = *(const s16x8*)(vb1 + kv);
            s16x8 vf11 = *(const s16x8*)(vb1 + kv + 16);
            // ---- causal mask (diagonal tile only) ----
            if (kv + 32 > q0) {
                const int qg = q0 + q;
#pragma unroll
                for (int i = 0; i < 16; ++i) {
                    int kk = kv + (i & 3) + 8 * (i >> 2) + khalf;
                    if (kk > qg) s[i] = -1e30f;
                }
            }
            // ---- row max (in-register + one half-swap) ----
            float mx = s[0];
#pragma unroll
            for (int i = 1; i < 16; ++i) mx = fmaxf(mx, s[i]);
            mx = fmaxf(mx, __shfl_xor(mx, 32));
            const float mnew = fmaxf(m, mx);
            const float corr = __expf(m - mnew);
            m = mnew;
            // ---- P = exp(S - m), row sum ----
            float rs = 0.0f;
#pragma unroll
            for (int i = 0; i < 16; ++i) {
                float p = __expf(s[i] - mnew);
                s[i] = p;
                rs += p;
            }
            rs += __shfl_xor(rs, 32);
            lsum = lsum * corr + rs;
#pragma unroll
            for (int i = 0; i < 16; ++i) { o0[i] *= corr; o1[i] *= corr; }
            // ---- pack P -> B-fragments (cvt_pk + half swaps) ----
            unsigned int cc[8], pc[8];
#pragma unroll
            for (int i = 0; i < 8; ++i) cc[i] = cvtpk_bf16(s[2 * i], s[2 * i + 1]);
#pragma unroll
            for (int i = 0; i < 8; ++i)
                pc[i] = (unsigned int)__shfl_xor((int)cc[i], 32);
            u32x4 w0, w1;
            w0[0] = hi ? pc[2] : cc[0]; w0[1] = hi ? pc[3] : cc[1];
            w0[2] = hi ? cc[2] : pc[0]; w0[3] = hi ? cc[3] : pc[1];
            w1[0] = hi ? pc[6] : cc[4]; w1[1] = hi ? pc[7] : cc[5];
            w1[2] = hi ? cc[6] : pc[4]; w1[3] = hi ? cc[7] : pc[5];
            s16x8 pb0 = __builtin_bit_cast(s16x8, w0);
            s16x8 pb1 = __builtin_bit_cast(s16x8, w1);
            // ---- O^T += V^T P^T ----
            __builtin_amdgcn_s_setprio(1);
            o0 = mfma32(vf00, pb0, o0);
            o0 = mfma32(vf01, pb1, o0);
            o1 = mfma32(vf10, pb0, o1);
            o1 = mfma32(vf11, pb1, o1);
            __builtin_amdgcn_s_setprio(0);
        }
    }

    // ---- stage A: waves 4..7 publish ----
    if (w >= 4) {
        const int sw = w - 4;
#pragma unroll
        for (int i = 0; i < 16; ++i) {
            int d = (i & 3) + 8 * (i >> 2) + khalf;
            solds[sw][q][d] = o0[i];
            solds[sw][q][d + 32] = o1[i];
        }
        if (!hi) { sml[sw][0][q] = m; sml[sw][1][q] = lsum; }
    }
    __syncthreads();
    // ---- stage B: waves 0..3 merge partner w+4 ----
    if (w < 4) {
        const float mp = sml[w][0][q], lp = sml[w][1][q];
        const float M = fmaxf(m, mp);
        const float e = __expf(m - M), ep = __expf(mp - M);
        m = M;
        lsum = lsum * e + lp * ep;
#pragma unroll
        for (int i = 0; i < 16; ++i) {
            int d = (i & 3) + 8 * (i >> 2) + khalf;
            o0[i] = o0[i] * e + solds[w][q][d] * ep;
            o1[i] = o1[i] * e + solds[w][q][d + 32] * ep;
        }
    }
    __syncthreads();
    if (w < 4) {
#pragma unroll
        for (int i = 0; i < 16; ++i) {
            int d = (i & 3) + 8 * (i >> 2) + khalf;
            solds[w][q][d] = o0[i];
            solds[w][q][d + 32] = o1[i];
        }
        if (!hi) { sml[w][0][q] = m; sml[w][1][q] = lsum; }
    }
    __syncthreads();
    // ---- final: 512 threads, 4 outputs each, coalesced f32x4 stores ----
    {
        const int t = threadIdx.x;
        const int qq = t >> 4, d0 = (t & 15) * 4;
        float M = -1e30f;
#pragma unroll
        for (int ww = 0; ww < 4; ++ww) M = fmaxf(M, sml[ww][0][qq]);
        float L = 0.0f;
        float O[4] = {0.0f, 0.0f, 0.0f, 0.0f};
#pragma unroll
        for (int ww = 0; ww < 4; ++ww) {
            float e = __expf(sml[ww][0][qq] - M);
            L += sml[ww][1][qq] * e;
#pragma unroll
            for (int j = 0; j < 4; ++j) O[j] += solds[ww][qq][d0 + j] * e;
        }
        f32x4 res;
#pragma unroll
        for (int j = 0; j < 4; ++j) res[j] = O[j] / L;
        *(f32x4*)(out + ((size_t)(b * SEQ_T + q0 + qq)) * 64 + d0) = res;
    }
}

// ---------------------------------------------------------------------------
extern "C" void kernel_launch(void* const* d_in, const int* in_sizes, int n_in,
                              void* d_out, int out_size, void* d_ws, size_t ws_size,
                              hipStream_t stream) {
    const float* x  = (const float*)d_in[0];
    const float* wq = (const float*)d_in[1];
    const float* bq = (const float*)d_in[2];
    const float* wk = (const float*)d_in[3];
    const float* bk = (const float*)d_in[4];
    const float* wv = (const float*)d_in[5];
    const float* bv = (const float*)d_in[6];
    float* out = (float*)d_out;

    char* ws = (char*)d_ws;
    unsigned short* wT    = (unsigned short*)(ws);                       // 384 KiB
    unsigned short* q_ws  = (unsigned short*)(ws + 393216);              // 2 MiB
    unsigned short* k_ws  = (unsigned short*)(ws + 393216 + 2097152);    // 2 MiB
    unsigned short* vT_ws = (unsigned short*)(ws + 393216 + 2 * 2097152);// 2 MiB

    wconv_kernel<<<dim3(768), dim3(256), 0, stream>>>(wq, wk, wv, wT);
    qkv_kernel<<<dim3(512), dim3(256), 0, stream>>>(x, bq, bk, bv, wT, q_ws, k_ws, vT_ws);
    attn_kernel<<<dim3(512), dim3(512), 0, stream>>>(q_ws, k_ws, vT_ws, out);
}

// Round 6
// 83.677 us; speedup vs baseline: 3.2619x; 1.3386x over previous
//
#include <hip/hip_runtime.h>
#include <hip/hip_bf16.h>

typedef __attribute__((ext_vector_type(4)))  float f32x4;
typedef __attribute__((ext_vector_type(16))) float f32x16;
typedef __attribute__((ext_vector_type(8)))  short s16x8;
typedef __attribute__((ext_vector_type(4)))  unsigned int u32x4;

#define D_MODEL 1024
#define D_HEAD  64
#define SEQ_T   4096

__device__ __forceinline__ unsigned short f2bf(float f) {
    unsigned int u = __float_as_uint(f);
    u += 0x7fffu + ((u >> 16) & 1u);
    return (unsigned short)(u >> 16);
}

__device__ __forceinline__ unsigned int cvtpk_bf16(float lo, float hi) {
    unsigned int r;
    asm("v_cvt_pk_bf16_f32 %0, %1, %2" : "=v"(r) : "v"(lo), "v"(hi));
    return r;
}

__device__ __forceinline__ f32x4 mfma16(s16x8 a, s16x8 b, f32x4 c) {
    return __builtin_amdgcn_mfma_f32_16x16x32_bf16(a, b, c, 0, 0, 0);
}
__device__ __forceinline__ f32x16 mfma32(s16x8 a, s16x8 b, f32x16 c) {
    return __builtin_amdgcn_mfma_f32_32x32x16_bf16(a, b, c, 0, 0, 0);
}

// ---------------------------------------------------------------------------
// Kernel 0: weights [1024][64] f32 (q,k,v) -> wT [192][1024] bf16 (transposed)
// ---------------------------------------------------------------------------
__global__ __launch_bounds__(256) void wconv_kernel(
    const float* __restrict__ wq, const float* __restrict__ wk,
    const float* __restrict__ wv, unsigned short* __restrict__ wT)
{
    int idx = blockIdx.x * 256 + threadIdx.x;        // [0, 3*65536)
    int mat = idx >> 16;
    int rem = idx & 65535;
    int k = rem >> 6, n = rem & 63;
    const float* w = (mat == 0) ? wq : (mat == 1) ? wk : wv;
    wT[(size_t)(mat * 64 + n) * D_MODEL + k] = f2bf(w[rem]);
}

// ---------------------------------------------------------------------------
// Kernel 1: fused QKV projection — 2-phase LDS-pipelined GEMM.
// BM=64, BN=96, BK=64.  Grid 512 = 256 M-blocks x 2 N-halves -> 2 blocks/CU.
// Block: 256 thr = 4 waves (2x2); wave = 32 rows x 48 cols (acc 6 f32x4).
// Double-buffered LDS: x tile [64][68] f32 (pad 68 -> conflict-free b128),
// wT tile [96][72] bf16 (pad 72 -> conflict-free).  Reg-staged loads issued
// 2 K-steps ahead; ds_write to opposite buffer; ONE barrier per K-step.
// q pre-scaled by 1/8 (exact).  v written transposed: vT[b][d][t].
// ---------------------------------------------------------------------------
__global__ __launch_bounds__(256, 2) void qkv_kernel(
    const float* __restrict__ x,
    const float* __restrict__ bq, const float* __restrict__ bk,
    const float* __restrict__ bv,
    const unsigned short* __restrict__ wT,
    unsigned short* __restrict__ q_ws, unsigned short* __restrict__ k_ws,
    unsigned short* __restrict__ vT_ws)
{
    __shared__ float xs[2][64 * 68];                 // 2 x 17408 B
    __shared__ unsigned short wls[2][96 * 72];       // 2 x 13824 B  (61 KiB total)
    const int t = threadIdx.x;
    const int lane = t & 63, w = t >> 6;
    const int wr = w >> 1, wc = w & 1;
    const int lr = lane & 15, lg = lane >> 4;
    const int mb = (int)blockIdx.x >> 1, nb = (int)blockIdx.x & 1;

    // staging source pointers (element units; add k0 per step)
    const float* xsrc = x + (size_t)(mb * 64 + (t >> 4)) * D_MODEL + (t & 15) * 4;
    const unsigned short* wsrc = wT + (size_t)(nb * 96 + (t >> 3)) * D_MODEL + (t & 7) * 8;

    f32x4 acc[2][3];
#pragma unroll
    for (int s = 0; s < 2; ++s)
#pragma unroll
        for (int c = 0; c < 3; ++c) acc[s][c] = (f32x4)0.0f;

    f32x4 xreg[4];
    u32x4 wreg[3];

#define GLOAD(K0) do {                                                         \
    _Pragma("unroll") for (int j = 0; j < 4; ++j)                              \
        xreg[j] = *(const f32x4*)(xsrc + (size_t)j * 16 * D_MODEL + (K0));     \
    _Pragma("unroll") for (int j = 0; j < 3; ++j)                              \
        wreg[j] = *(const u32x4*)(wsrc + (size_t)j * 32 * D_MODEL + (K0));     \
} while (0)

#define DSWRITE(BUF) do {                                                      \
    float* XB = &xs[BUF][0]; unsigned short* WB = &wls[BUF][0];                \
    _Pragma("unroll") for (int j = 0; j < 4; ++j)                              \
        *(f32x4*)(XB + ((t >> 4) + j * 16) * 68 + (t & 15) * 4) = xreg[j];     \
    _Pragma("unroll") for (int j = 0; j < 3; ++j)                              \
        *(u32x4*)(WB + ((t >> 3) + j * 32) * 72 + (t & 7) * 8) = wreg[j];      \
} while (0)

#define COMPUTE(BUF) do {                                                      \
    const float* XB = &xs[BUF][0]; const unsigned short* WB = &wls[BUF][0];    \
    _Pragma("unroll") for (int ks = 0; ks < 2; ++ks) {                         \
        s16x8 af[2];                                                           \
        _Pragma("unroll") for (int sub = 0; sub < 2; ++sub) {                  \
            const float* ap = XB + (wr * 32 + sub * 16 + lr) * 68 + ks * 32 + lg * 8; \
            f32x4 a0 = *(const f32x4*)ap, a1 = *(const f32x4*)(ap + 4);        \
            u32x4 pk;                                                          \
            pk[0] = cvtpk_bf16(a0[0], a0[1]); pk[1] = cvtpk_bf16(a0[2], a0[3]);\
            pk[2] = cvtpk_bf16(a1[0], a1[1]); pk[3] = cvtpk_bf16(a1[2], a1[3]);\
            af[sub] = __builtin_bit_cast(s16x8, pk);                           \
        }                                                                      \
        _Pragma("unroll") for (int tc = 0; tc < 3; ++tc) {                     \
            s16x8 bf = *(const s16x8*)(WB + (wc * 48 + tc * 16 + lr) * 72 + ks * 32 + lg * 8); \
            acc[0][tc] = mfma16(af[0], bf, acc[0][tc]);                        \
            acc[1][tc] = mfma16(af[1], bf, acc[1][tc]);                        \
        }                                                                      \
    }                                                                          \
} while (0)

    // prologue: stage tile 0, issue tile 1
    GLOAD(0);
    DSWRITE(0);
    GLOAD(64);
    __syncthreads();

    for (int step = 0; step < 16; ++step) {
        const int cur = step & 1;
        if (step + 1 < 16) DSWRITE(cur ^ 1);         // write next tile (regs ready)
        if (step + 2 < 16) GLOAD((step + 2) * 64);   // issue loads 2 steps ahead
        COMPUTE(cur);
        __syncthreads();                             // one barrier per K-step
    }

#undef GLOAD
#undef DSWRITE
#undef COMPUTE

    // epilogue: bias + dtype-split writes
#pragma unroll
    for (int sub = 0; sub < 2; ++sub)
#pragma unroll
        for (int tc = 0; tc < 3; ++tc) {
            int col = nb * 96 + wc * 48 + tc * 16 + lr;
            float bias = (col < 64) ? bq[col] : (col < 128) ? bk[col - 64] : bv[col - 128];
#pragma unroll
            for (int r = 0; r < 4; ++r) {
                int row = mb * 64 + wr * 32 + sub * 16 + lg * 4 + r;   // = b*4096 + t
                float v = acc[sub][tc][r] + bias;
                if (col < 64) {
                    q_ws[(size_t)row * 64 + col] = f2bf(v * 0.125f);   // fold softmax scale
                } else if (col < 128) {
                    k_ws[(size_t)row * 64 + (col - 64)] = f2bf(v);
                } else {
                    int b = row >> 12, tt = row & 4095;
                    vT_ws[(size_t)(b * 64 + (col - 128)) * SEQ_T + tt] = f2bf(v);
                }
            }
        }
}

// ---------------------------------------------------------------------------
// Kernel 2: causal flash attention, swapped-QK in-register softmax (32x32).
// Block: 512 thr = 8 waves, all on the same 32 q-rows; wave w handles kv
// tiles c = w, w+8, ... (KVBLK=32).  No LDS / barriers in main loop.
// Two-stage (8->4->1) LDS combine.  Blocks ordered longest-q0-first.
// ---------------------------------------------------------------------------
__global__ __launch_bounds__(512) void attn_kernel(
    const unsigned short* __restrict__ q_ws, const unsigned short* __restrict__ k_ws,
    const unsigned short* __restrict__ vT_ws, float* __restrict__ out)
{
    __shared__ float solds[4][32][66];               // 33 KiB
    __shared__ float sml[4][2][32];                  // 1 KiB
    const int lane = threadIdx.x & 63;
    const int w = threadIdx.x >> 6;                  // 0..7
    const int q = lane & 31;
    const int hi = lane >> 5;
    const int khalf = 4 * hi;
    const int b = blockIdx.x & 3;
    const int qb = blockIdx.x >> 2;                  // 0..127
    const int q0 = SEQ_T - 32 * (qb + 1);            // longest first
    const int ntiles = (q0 >> 5) + 1;

    // Q B-fragments (col = q = lane&31, k-dim d = hi*8 + j + 16*dstep)
    const unsigned short* qrow = q_ws + ((size_t)(b * SEQ_T + q0 + q)) * 64 + hi * 8;
    s16x8 qf[4];
#pragma unroll
    for (int d = 0; d < 4; ++d) qf[d] = *(const s16x8*)(qrow + d * 16);

    f32x16 o0 = (f32x16)0.0f, o1 = (f32x16)0.0f;
    float m = -1e30f, lsum = 0.0f;

    const unsigned short* kbase = k_ws + ((size_t)(b * SEQ_T + q)) * 64 + hi * 8;
    const unsigned short* vb0 = vT_ws + ((size_t)(b * 64 + q)) * SEQ_T + hi * 8;
    const unsigned short* vb1 = vT_ws + ((size_t)(b * 64 + 32 + q)) * SEQ_T + hi * 8;

    int c = w;
    if (c < ntiles) {
        s16x8 kf[4];
        {
            const unsigned short* kp = kbase + (size_t)(c << 5) * 64;
#pragma unroll
            for (int d = 0; d < 4; ++d) kf[d] = *(const s16x8*)(kp + d * 16);
        }
        for (; c < ntiles; c += 8) {
            const int kv = c << 5;
            // ---- S^T = K Q^T ----
            f32x16 s = (f32x16)0.0f;
#pragma unroll
            for (int d = 0; d < 4; ++d) s = mfma32(kf[d], qf[d], s);
            // ---- prefetch next K tile ----
            {
                const int cn = (c + 8 < ntiles) ? c + 8 : 0;
                const unsigned short* kp = kbase + (size_t)(cn << 5) * 64;
#pragma unroll
                for (int d = 0; d < 4; ++d) kf[d] = *(const s16x8*)(kp + d * 16);
            }
            // ---- V^T A-fragments for this tile ----
            s16x8 vf00 = *(const s16x8*)(vb0 + kv);
            s16x8 vf01 = *(const s16x8*)(vb0 + kv + 16);
            s16x8 vf10 = *(const s16x8*)(vb1 + kv);
            s16x8 vf11 = *(const s16x8*)(vb1 + kv + 16);
            // ---- causal mask (diagonal tile only) ----
            if (kv + 32 > q0) {
                const int qg = q0 + q;
#pragma unroll
                for (int i = 0; i < 16; ++i) {
                    int kk = kv + (i & 3) + 8 * (i >> 2) + khalf;
                    if (kk > qg) s[i] = -1e30f;
                }
            }
            // ---- row max (in-register + one half-swap) ----
            float mx = s[0];
#pragma unroll
            for (int i = 1; i < 16; ++i) mx = fmaxf(mx, s[i]);
            mx = fmaxf(mx, __shfl_xor(mx, 32));
            const float mnew = fmaxf(m, mx);
            const float corr = __expf(m - mnew);
            m = mnew;
            // ---- P = exp(S - m), row sum ----
            float rs = 0.0f;
#pragma unroll
            for (int i = 0; i < 16; ++i) {
                float p = __expf(s[i] - mnew);
                s[i] = p;
                rs += p;
            }
            rs += __shfl_xor(rs, 32);
            lsum = lsum * corr + rs;
#pragma unroll
            for (int i = 0; i < 16; ++i) { o0[i] *= corr; o1[i] *= corr; }
            // ---- pack P -> B-fragments (cvt_pk + half swaps) ----
            unsigned int cc[8], pc[8];
#pragma unroll
            for (int i = 0; i < 8; ++i) cc[i] = cvtpk_bf16(s[2 * i], s[2 * i + 1]);
#pragma unroll
            for (int i = 0; i < 8; ++i)
                pc[i] = (unsigned int)__shfl_xor((int)cc[i], 32);
            u32x4 w0, w1;
            w0[0] = hi ? pc[2] : cc[0]; w0[1] = hi ? pc[3] : cc[1];
            w0[2] = hi ? cc[2] : pc[0]; w0[3] = hi ? cc[3] : pc[1];
            w1[0] = hi ? pc[6] : cc[4]; w1[1] = hi ? pc[7] : cc[5];
            w1[2] = hi ? cc[6] : pc[4]; w1[3] = hi ? cc[7] : pc[5];
            s16x8 pb0 = __builtin_bit_cast(s16x8, w0);
            s16x8 pb1 = __builtin_bit_cast(s16x8, w1);
            // ---- O^T += V^T P^T ----
            o0 = mfma32(vf00, pb0, o0);
            o0 = mfma32(vf01, pb1, o0);
            o1 = mfma32(vf10, pb0, o1);
            o1 = mfma32(vf11, pb1, o1);
        }
    }

    // ---- stage A: waves 4..7 publish ----
    if (w >= 4) {
        const int sw = w - 4;
#pragma unroll
        for (int i = 0; i < 16; ++i) {
            int d = (i & 3) + 8 * (i >> 2) + khalf;
            solds[sw][q][d] = o0[i];
            solds[sw][q][d + 32] = o1[i];
        }
        if (!hi) { sml[sw][0][q] = m; sml[sw][1][q] = lsum; }
    }
    __syncthreads();
    // ---- stage B: waves 0..3 merge partner w+4 ----
    if (w < 4) {
        const float mp = sml[w][0][q], lp = sml[w][1][q];
        const float M = fmaxf(m, mp);
        const float e = __expf(m - M), ep = __expf(mp - M);
        m = M;
        lsum = lsum * e + lp * ep;
#pragma unroll
        for (int i = 0; i < 16; ++i) {
            int d = (i & 3) + 8 * (i >> 2) + khalf;
            o0[i] = o0[i] * e + solds[w][q][d] * ep;
            o1[i] = o1[i] * e + solds[w][q][d + 32] * ep;
        }
    }
    __syncthreads();
    if (w < 4) {
#pragma unroll
        for (int i = 0; i < 16; ++i) {
            int d = (i & 3) + 8 * (i >> 2) + khalf;
            solds[w][q][d] = o0[i];
            solds[w][q][d + 32] = o1[i];
        }
        if (!hi) { sml[w][0][q] = m; sml[w][1][q] = lsum; }
    }
    __syncthreads();
    // ---- final: 512 threads, 4 outputs each, coalesced f32x4 stores ----
    {
        const int t = threadIdx.x;
        const int qq = t >> 4, d0 = (t & 15) * 4;
        float M = -1e30f;
#pragma unroll
        for (int ww = 0; ww < 4; ++ww) M = fmaxf(M, sml[ww][0][qq]);
        float L = 0.0f;
        float O[4] = {0.0f, 0.0f, 0.0f, 0.0f};
#pragma unroll
        for (int ww = 0; ww < 4; ++ww) {
            float e = __expf(sml[ww][0][qq] - M);
            L += sml[ww][1][qq] * e;
#pragma unroll
            for (int j = 0; j < 4; ++j) O[j] += solds[ww][qq][d0 + j] * e;
        }
        f32x4 res;
#pragma unroll
        for (int j = 0; j < 4; ++j) res[j] = O[j] / L;
        *(f32x4*)(out + ((size_t)(b * SEQ_T + q0 + qq)) * 64 + d0) = res;
    }
}

// ---------------------------------------------------------------------------
extern "C" void kernel_launch(void* const* d_in, const int* in_sizes, int n_in,
                              void* d_out, int out_size, void* d_ws, size_t ws_size,
                              hipStream_t stream) {
    const float* x  = (const float*)d_in[0];
    const float* wq = (const float*)d_in[1];
    const float* bq = (const float*)d_in[2];
    const float* wk = (const float*)d_in[3];
    const float* bk = (const float*)d_in[4];
    const float* wv = (const float*)d_in[5];
    const float* bv = (const float*)d_in[6];
    float* out = (float*)d_out;

    char* ws = (char*)d_ws;
    unsigned short* wT    = (unsigned short*)(ws);                       // 384 KiB
    unsigned short* q_ws  = (unsigned short*)(ws + 393216);              // 2 MiB
    unsigned short* k_ws  = (unsigned short*)(ws + 393216 + 2097152);    // 2 MiB
    unsigned short* vT_ws = (unsigned short*)(ws + 393216 + 2 * 2097152);// 2 MiB

    wconv_kernel<<<dim3(768), dim3(256), 0, stream>>>(wq, wk, wv, wT);
    qkv_kernel<<<dim3(512), dim3(256), 0, stream>>>(x, bq, bk, bv, wT, q_ws, k_ws, vT_ws);
    attn_kernel<<<dim3(512), dim3(512), 0, stream>>>(q_ws, k_ws, vT_ws, out);
}